// Round 9
// baseline (48.817 us; speedup 1.0000x reference)
//
#include <hip/hip_runtime.h>

// Sequential 1001-step closed-loop double-integrator sim with teacher forcing
// and early stopping. Inherently serial (nonlinear v/p recurrence).
// R9: issue-bound (R8 proved chain-shortening neutral, heater neutral) ->
// cut instructions/step via tf-step algebra:
//   tf step:  pn = p*alpha, vn = pn*obar, o = obar   (alpha = 1+DT*u,
//             obar = u/alpha precomputed; output PRESTORED during staging)
//   non-tf:   R8's folded form (proven absmax 0.0), v carried
// Per-step uniform branch on a per-block ballot mask (SALU bitcmp+cbranch);
// readlane with immediate index after full unroll; per-block ballot stop
// check + early break (R7-proven); speculative stores fixed by tail-zero.

#define N_STEPS 1001
#define DT_F 0.05f
#define LO_F 0.05f
#define HI_F 1000.0f

__device__ __forceinline__ float fast_rcp(float x) {
    return __builtin_amdgcn_rcpf(x);
}
__device__ __forceinline__ float rl_f(float x, int i) {
    return __int_as_float(__builtin_amdgcn_readlane(__float_as_int(x), i));
}

// one simulation step; i is a compile-time-constant lane index after unroll.
// Xc = tf ? alpha : c1w*u ; Yc = tf ? obar : u ; m = block tf bitmask.
#define SIM_STEP(i, ob) do {                                        \
    if ((m >> (i)) & 1ull) {                                        \
        const float al_ = rl_f(Xc, (i));                            \
        const float ob_ = rl_f(Yc, (i));                            \
        p = p * al_;                                                \
        v = p * ob_;            /* = p_new*obar ~= p_old*u */       \
        o = ob_;                /* out[k] prestored in staging */   \
        pblk = (lane == (i)) ? p : pblk;                            \
    } else {                                                        \
        const float ca_ = rl_f(Xc, (i));   /* c1w*u */              \
        const float u_  = rl_f(Yc, (i));                            \
        const float pa_ = p + ca_;                                  \
        const float X_  = fmaf(DT_F, v, pa_);                       \
        const float pn_ = fmaf(nc1w, o, X_);  /* p+DT*v+c1w*(u-o) */\
        const float d_  = u_ - o;                                   \
        const float vn_ = fmaf(dwv, d_, v);   /* v+dw*(u-o) */      \
        const float rq_ = fast_rcp(pn_);                            \
        o = vn_ * rq_;                                              \
        (ob)[(i)] = o;                                              \
        pblk = (lane == (i)) ? pn_ : pblk;                          \
        p = pn_; v = vn_;                                           \
    }                                                               \
} while (0)

__global__ __launch_bounds__(64) void sim_scan_kernel(
    const float* __restrict__ inputs,
    const float* __restrict__ fc1_w,
    const void* __restrict__ tf_mask,
    float* __restrict__ out)
{
    __shared__ float sX[1088], sY[1088], sT[1088];
    const int lane = threadIdx.x;   // one wave

    // --- tf_mask element-width detection, wave-parallel ---
    // int32 0/1: bytes at i%4!=0 all zero. int64 0/1: additionally i%8==4
    // zero. 1-byte bool: ~300 random 0/1 bytes in 1..399 -> nonzero with
    // prob 1 - 2^-300.
    const unsigned char* mb = (const unsigned char*)tf_mask;
    bool nm4 = false, m84 = false;
    for (int i = 1 + lane; i < 400; i += 64) {
        unsigned char b = mb[i];
        if (b) { if ((i & 3) != 0) nm4 = true; else if ((i & 7) == 4) m84 = true; }
    }
    const int width = __any(nm4) ? 1 : (__any(m84) ? 4 : 8);

    const float w   = fc1_w[0];
    const float c1w = (DT_F * DT_F * 0.5f) * w;   // 0.00125*w
    const float dwv = DT_F * w;                    // 0.05*w
    const float nc1w = -c1w;

    // --- staging: per-step constants into LDS; tf outputs PRESTORED ---
    for (int j = 0; j < 17; ++j) {
        const int k = j * 64 + lane;     // k < 1088
        float u = 0.0f; bool tf = false;
        if (k < N_STEPS) {
            u = inputs[k];
            if (width == 1)      tf = mb[k] != 0;
            else if (width == 4) tf = ((const int*)tf_mask)[k] != 0;
            else                 tf = ((const long long*)tf_mask)[k] != 0;
        }
        const float al = fmaf(DT_F, u, 1.0f);      // 1 + DT*u
        const float obr = u * fast_rcp(al);        // u/(1+DT*u)
        sX[k] = tf ? al  : c1w * u;
        sY[k] = tf ? obr : u;
        sT[k] = tf ? 1.0f : 0.0f;
        if (tf && k < N_STEPS) out[k] = obr;       // state-independent output
    }

    // All 64 lanes run the scan redundantly (identical values, no divergence).
    float p = 100.0f, v = 0.0f, o = 0.0f;  // o = v/p = 0 initially
    int  kstop = N_STEPS - 1;
    bool hit = false;

    float Xc = sX[lane], Yc = sY[lane], Tc = sT[lane];

    for (int j = 0; j < 15; ++j) {          // 15 full 64-step blocks
        // prefetch next block's constants (hidden under this block's compute)
        const int kn = (j + 1) * 64 + lane;
        const float Xn = sX[kn], Yn = sY[kn], Tn = sT[kn];

        const unsigned long long m = __ballot(Tc != 0.0f);
        float pblk = 100.0f;                // in-range default
        float* ob = out + j * 64;
#pragma unroll
        for (int i = 0; i < 64; ++i) SIM_STEP(i, ob);

        // first OOB step in this block, if any (speculation fixed by ctz)
        const unsigned long long hm = __ballot((pblk < LO_F) || (pblk > HI_F));
        if (hm) { kstop = j * 64 + (__ffsll(hm) - 1); hit = true; break; }

        Xc = Xn; Yc = Yn; Tc = Tn;
    }

    if (!hit) {                              // tail block: 41 steps
        const unsigned long long m = __ballot(Tc != 0.0f);
        float pblk = 100.0f;
        float* ob = out + 960;
#pragma unroll
        for (int i = 0; i < 41; ++i) SIM_STEP(i, ob);
        const unsigned long long hm = __ballot((pblk < LO_F) || (pblk > HI_F));
        if (hm) kstop = 960 + (__ffsll(hm) - 1);
    }

    // drain speculative/prestored stores, then zero everything past the stop
    asm volatile("s_waitcnt vmcnt(0)" ::: "memory");
    for (int k2 = kstop + 1 + lane; k2 < N_STEPS; k2 += 64) out[k2] = 0.0f;
    out[N_STEPS] = (float)kstop;   // k_stop as float (flat f32 output)
}

extern "C" void kernel_launch(void* const* d_in, const int* in_sizes, int n_in,
                              void* d_out, int out_size, void* d_ws, size_t ws_size,
                              hipStream_t stream) {
    const float* inputs = (const float*)d_in[0];
    const float* fc1_w  = (const float*)d_in[1];
    const void*  tfm    = d_in[2];
    (void)in_sizes; (void)n_in; (void)out_size; (void)d_ws; (void)ws_size;

    sim_scan_kernel<<<dim3(1), dim3(64), 0, stream>>>(
        inputs, fc1_w, tfm, (float*)d_out);
}

// Round 10
// 28.375 us; speedup vs baseline: 1.7204x; 1.7204x over previous
//
#include <hip/hip_runtime.h>

// 1001-step closed-loop sim, reformulated as a PARALLEL fixed-point scan.
// Key algebra: given r_k = v_in/p_in (= previous output o_{k-1}), each step is
// affine in (p,v):   non-tf: A=[[1,DT],[0,1]], c=(c1w*(u-r), dw*(u-r))
//                    tf:     A=[[al,0],[u,0]], c=0, al=1+DT*u (net_in ~= 0)
// So: Jacobi sweeps — guess r from last sweep's o, prefix-compose the 1001
// affine maps (16 waves x 64-lane shuffle scans + LDS chunk-carry), apply to
// s0=(100,0), recompute o = vn*rcp(pn). tf steps (~50%) have o independent of
// state -> seed is half-exact; contraction ~0.05*w/step -> 7 sweeps converge
// to ~1e-3 (threshold 16.96). Stop/kstop: first k with pn OOB on the final
// sweep; outputs masked after kstop (post-stop NaN/inf are beyond kstop by
// construction since blowups require leaving [LO,HI] first).

#define N_STEPS 1001
#define DT_F 0.05f
#define LO_F 0.05f
#define HI_F 1000.0f
#define NSWEEPS 7
#define NTHREADS 1024
#define NWAVES 16

__device__ __forceinline__ float fast_rcp(float x) {
    return __builtin_amdgcn_rcpf(x);
}

__global__ __launch_bounds__(NTHREADS) void sim_scan_kernel(
    const float* __restrict__ inputs,
    const float* __restrict__ fc1_w,
    const void* __restrict__ tf_mask,
    float* __restrict__ out)
{
    __shared__ float oL[NTHREADS + 2];        // oL[k] = o_{k-1}; oL[0] = 0 fixed
    __shared__ float tot[NWAVES][8];          // chunk-total maps (6 floats used)
    __shared__ unsigned long long wm[NWAVES]; // per-wave hit masks

    const int tid  = threadIdx.x;
    const int lane = tid & 63;
    const int wave = tid >> 6;
    const int k    = tid;                     // step index owned by this thread
    const bool real = (k < N_STEPS);

    // --- tf_mask element-width detection (each wave redundantly, same answer)
    // int32 0/1: bytes at i%4!=0 all zero; int64 adds i%8==4 zero; 1-byte
    // bool: ~300 random 0/1 bytes in 1..399 -> nonzero w.p. 1-2^-300.
    const unsigned char* mb = (const unsigned char*)tf_mask;
    bool nm4 = false, m84 = false;
    for (int i = 1 + lane; i < 400; i += 64) {
        unsigned char b = mb[i];
        if (b) { if ((i & 3) != 0) nm4 = true; else if ((i & 7) == 4) m84 = true; }
    }
    const int width = __any(nm4) ? 1 : (__any(m84) ? 4 : 8);

    // --- load per-step u, tf ---
    float u = 0.0f; bool tf = false;
    if (real) {
        u = inputs[k];
        if (width == 1)      tf = mb[k] != 0;
        else if (width == 4) tf = ((const int*)tf_mask)[k] != 0;
        else                 tf = ((const long long*)tf_mask)[k] != 0;
    }

    const float w   = fc1_w[0];
    const float c1w = (DT_F * DT_F * 0.5f) * w;   // 0.00125*w
    const float dw  = DT_F * w;                    // 0.05*w

    // --- sweep-invariant per-step map pieces (pads: identity-ish, c=0) ---
    const float al  = fmaf(DT_F, u, 1.0f);        // 1 + DT*u
    const float b00 = tf ? al   : 1.0f;
    const float b01 = tf ? 0.0f : DT_F;
    const float b10 = tf ? u    : 0.0f;
    const float b11 = tf ? 0.0f : 1.0f;
    const float Kc0 = (tf || !real) ? 0.0f : c1w;
    const float Kc1 = (tf || !real) ? 0.0f : dw;

    // --- seed o-guesses: tf steps' o = u/al is state-independent (exact) ---
    if (tid == 0) oL[0] = 0.0f;                   // r_0 = v0/p0 = 0, fixed
    oL[k + 1] = (real && tf) ? (u * fast_rcp(al)) : 0.0f;

    float o = 0.0f, pn = 100.0f;                  // final-sweep results

    for (int sw = 0; sw < NSWEEPS; ++sw) {
        __syncthreads();                          // oL (prev sweep) ready
        // rebuild const-vector from current r-guess
        const float r  = oL[k];
        const float dd = u - r;
        const float c0 = Kc0 * dd;                // pads: 0*anything = 0
        const float c1 = Kc1 * dd;

        // --- chunk-local inclusive scan (Hillis-Steele over 64 lanes) ---
        // compose(self=later, other=earlier): A=As*Ao, c=As*co+cs
        float s00 = b00, s01 = b01, s10 = b10, s11 = b11, sc0 = c0, sc1 = c1;
#pragma unroll
        for (int d = 1; d < 64; d <<= 1) {
            const float t00 = __shfl_up(s00, (unsigned)d, 64);
            const float t01 = __shfl_up(s01, (unsigned)d, 64);
            const float t10 = __shfl_up(s10, (unsigned)d, 64);
            const float t11 = __shfl_up(s11, (unsigned)d, 64);
            const float tc0 = __shfl_up(sc0, (unsigned)d, 64);
            const float tc1 = __shfl_up(sc1, (unsigned)d, 64);
            if (lane >= d) {
                const float n00 = fmaf(s00, t00, s01 * t10);
                const float n01 = fmaf(s00, t01, s01 * t11);
                const float n10 = fmaf(s10, t00, s11 * t10);
                const float n11 = fmaf(s10, t01, s11 * t11);
                const float nc0 = fmaf(s00, tc0, fmaf(s01, tc1, sc0));
                const float nc1 = fmaf(s10, tc0, fmaf(s11, tc1, sc1));
                s00 = n00; s01 = n01; s10 = n10; s11 = n11;
                sc0 = nc0; sc1 = nc1;
            }
        }
        // post chunk totals (lane 63 holds the full-chunk composition)
        if (lane == 63) {
            tot[wave][0] = s00; tot[wave][1] = s01; tot[wave][2] = s10;
            tot[wave][3] = s11; tot[wave][4] = sc0; tot[wave][5] = sc1;
        }
        __syncthreads();                          // totals ready

        // --- each wave folds carries 0..wave-1 (uniform within wave) ---
        float sp = 100.0f, sv = 0.0f;             // s0 = (100, 0)
        for (int j = 0; j < wave; ++j) {
            const float a0 = tot[j][0], a1 = tot[j][1];
            const float a2 = tot[j][2], a3 = tot[j][3];
            const float e0 = tot[j][4], e1 = tot[j][5];
            const float np = fmaf(a0, sp, fmaf(a1, sv, e0));
            const float nv = fmaf(a2, sp, fmaf(a3, sv, e1));
            sp = np; sv = nv;
        }

        // --- apply this lane's prefix map: state AFTER step k ---
        pn = fmaf(s00, sp, fmaf(s01, sv, sc0));
        const float vn = fmaf(s10, sp, fmaf(s11, sv, sc1));
        o = vn * fast_rcp(pn);
        oL[k + 1] = real ? o : 0.0f;              // pads write 0 (keep NaN out)
    }

    // --- stop detection on final-sweep trajectory ---
    const bool hit = real && ((pn < LO_F) || (pn > HI_F));  // NaN -> false (post-stop only)
    const unsigned long long m = __ballot(hit);
    if (lane == 0) wm[wave] = m;
    __syncthreads();

    int kstop = N_STEPS - 1;                      // covers no-hit & hit-at-last
    bool found = false;
    for (int j = 0; j < NWAVES; ++j) {
        const unsigned long long mj = wm[j];
        if (!found && mj) { kstop = j * 64 + (__ffsll(mj) - 1); found = true; }
    }

    if (real) out[k] = (k <= kstop) ? o : 0.0f;   // out emitted on hit step too
    if (tid == N_STEPS) out[N_STEPS] = (float)kstop;
}

extern "C" void kernel_launch(void* const* d_in, const int* in_sizes, int n_in,
                              void* d_out, int out_size, void* d_ws, size_t ws_size,
                              hipStream_t stream) {
    const float* inputs = (const float*)d_in[0];
    const float* fc1_w  = (const float*)d_in[1];
    const void*  tfm    = d_in[2];
    (void)in_sizes; (void)n_in; (void)out_size; (void)d_ws; (void)ws_size;

    sim_scan_kernel<<<dim3(1), dim3(NTHREADS), 0, stream>>>(
        inputs, fc1_w, tfm, (float*)d_out);
}

// Round 11
// 16.574 us; speedup vs baseline: 2.9454x; 1.7120x over previous
//
#include <hip/hip_runtime.h>

// 1001-step closed-loop sim as a PARALLEL fixed-point affine scan (R10 base).
// R11: sweep-invariant A-matrices computed ONCE (sweep 0 full 6-float scan,
// saving per-round window products wA[d] + per-wave A-totals); sweeps 1+ are
// cheap c-only scans (2 shuffles + 4 fma per round). Cross-wave r derived
// from each lane-0's own carry fold (bitwise = neighbor wave's o) -> no oL
// LDS array; double-buffered c-totals -> ONE barrier per sweep. NSWEEPS 7->5
// (contraction ~1e-2/sweep; 5 is past float32 convergence; sweeps are
// arithmetic-identical to R10 which hit absmax 0.0).

#define N_STEPS 1001
#define DT_F 0.05f
#define LO_F 0.05f
#define HI_F 1000.0f
#define NSWEEPS 5
#define NTHREADS 1024
#define NWAVES 16

__device__ __forceinline__ float fast_rcp(float x) {
    return __builtin_amdgcn_rcpf(x);
}

__global__ __launch_bounds__(NTHREADS) void sim_scan_kernel(
    const float* __restrict__ inputs,
    const float* __restrict__ fc1_w,
    const void* __restrict__ tf_mask,
    float* __restrict__ out)
{
    __shared__ float totA[NWAVES][4];          // per-wave chunk A-products (sweep-invariant)
    __shared__ float totc[2][NWAVES][2];       // per-wave chunk c-totals (double-buffered)
    __shared__ unsigned long long wm[NWAVES];  // per-wave hit masks

    const int tid  = threadIdx.x;
    const int lane = tid & 63;
    const int wave = tid >> 6;
    const int k    = tid;
    const bool real = (k < N_STEPS);

    // --- tf_mask element-width detection (each wave redundantly, same answer)
    // int32 0/1: bytes at i%4!=0 all zero; int64 adds i%8==4 zero; 1-byte
    // bool: ~300 random 0/1 bytes in 1..399 -> nonzero w.p. 1-2^-300.
    const unsigned char* mb = (const unsigned char*)tf_mask;
    bool nm4 = false, m84 = false;
    for (int i = 1 + lane; i < 400; i += 64) {
        unsigned char b = mb[i];
        if (b) { if ((i & 3) != 0) nm4 = true; else if ((i & 7) == 4) m84 = true; }
    }
    const int width = __any(nm4) ? 1 : (__any(m84) ? 4 : 8);

    // --- per-step inputs (and step k-1's, for the r-seed) ---
    float u = 0.0f;  bool tf  = false;
    float u2 = 0.0f; bool tf2 = false;
    if (real) {
        u = inputs[k];
        if (width == 1)      tf = mb[k] != 0;
        else if (width == 4) tf = ((const int*)tf_mask)[k] != 0;
        else                 tf = ((const long long*)tf_mask)[k] != 0;
        if (k > 0) {
            u2 = inputs[k - 1];
            if (width == 1)      tf2 = mb[k - 1] != 0;
            else if (width == 4) tf2 = ((const int*)tf_mask)[k - 1] != 0;
            else                 tf2 = ((const long long*)tf_mask)[k - 1] != 0;
        }
    }

    const float w   = fc1_w[0];
    const float c1w = (DT_F * DT_F * 0.5f) * w;   // 0.00125*w
    const float dw  = DT_F * w;                    // 0.05*w

    // sweep-invariant per-step affine map A (pads: non-tf identity-shear, c=0)
    const float al  = fmaf(DT_F, u, 1.0f);        // 1 + DT*u
    const float b00 = tf ? al   : 1.0f;
    const float b01 = tf ? 0.0f : DT_F;
    const float b10 = tf ? u    : 0.0f;
    const float b11 = tf ? 0.0f : 1.0f;
    const bool  liveC = real && !tf;              // select (not mul-by-0): blocks NaN leak

    // seed r = o_{k-1} guess: exact where step k-1 is teacher-forced
    float r = 0.0f;
    if (k > 0 && tf2) r = u2 * fast_rcp(fmaf(DT_F, u2, 1.0f));

    float wA00[6], wA01[6], wA10[6], wA11[6];     // per-round window A products
    float F00, F01, F10, F11;                     // full-window A (after 6 rounds)
    float o = 0.0f, pn = 100.0f;

    // ---- sweep 0: full 6-float affine scan; save window/total A's ----
    {
        float s00 = b00, s01 = b01, s10 = b10, s11 = b11;
        const float dd = u - r;
        float sc0 = liveC ? c1w * dd : 0.0f;
        float sc1 = liveC ? dw  * dd : 0.0f;
#pragma unroll
        for (int ds = 0; ds < 6; ++ds) {
            const int d = 1 << ds;
            wA00[ds] = s00; wA01[ds] = s01; wA10[ds] = s10; wA11[ds] = s11;
            const float t00 = __shfl_up(s00, d, 64);
            const float t01 = __shfl_up(s01, d, 64);
            const float t10 = __shfl_up(s10, d, 64);
            const float t11 = __shfl_up(s11, d, 64);
            const float tc0 = __shfl_up(sc0, d, 64);
            const float tc1 = __shfl_up(sc1, d, 64);
            if (lane >= d) {
                const float n00 = fmaf(s00, t00, s01 * t10);
                const float n01 = fmaf(s00, t01, s01 * t11);
                const float n10 = fmaf(s10, t00, s11 * t10);
                const float n11 = fmaf(s10, t01, s11 * t11);
                const float nc0 = fmaf(s00, tc0, fmaf(s01, tc1, sc0));
                const float nc1 = fmaf(s10, tc0, fmaf(s11, tc1, sc1));
                s00 = n00; s01 = n01; s10 = n10; s11 = n11;
                sc0 = nc0; sc1 = nc1;
            }
        }
        F00 = s00; F01 = s01; F10 = s10; F11 = s11;
        if (lane == 63) {
            totA[wave][0] = s00; totA[wave][1] = s01;
            totA[wave][2] = s10; totA[wave][3] = s11;
            totc[0][wave][0] = sc0; totc[0][wave][1] = sc1;
        }
        __syncthreads();
        float sp = 100.0f, sv = 0.0f;             // s0 = (100, 0)
        for (int j = 0; j < wave; ++j) {
            const float np = fmaf(totA[j][0], sp, fmaf(totA[j][1], sv, totc[0][j][0]));
            const float nv = fmaf(totA[j][2], sp, fmaf(totA[j][3], sv, totc[0][j][1]));
            sp = np; sv = nv;
        }
        pn = fmaf(F00, sp, fmaf(F01, sv, sc0));
        const float vn = fmaf(F10, sp, fmaf(F11, sv, sc1));
        o = vn * fast_rcp(pn);
        // next r: within-wave shift; lane0 derives prev-wave-end o from its
        // own fold (bitwise-identical fma nesting to that lane's pn/vn/o)
        const float rr = __shfl_up(o, 1, 64);
        r = (lane == 0) ? sv * fast_rcp(sp) : rr;
    }

    // ---- sweeps 1..NSWEEPS-1: cheap c-only scans (A's reused) ----
    for (int sw = 1; sw < NSWEEPS; ++sw) {
        const float dd = u - r;
        float sc0 = liveC ? c1w * dd : 0.0f;
        float sc1 = liveC ? dw  * dd : 0.0f;
#pragma unroll
        for (int ds = 0; ds < 6; ++ds) {
            const int d = 1 << ds;
            const float tc0 = __shfl_up(sc0, d, 64);
            const float tc1 = __shfl_up(sc1, d, 64);
            if (lane >= d) {
                const float n0 = fmaf(wA00[ds], tc0, fmaf(wA01[ds], tc1, sc0));
                const float n1 = fmaf(wA10[ds], tc0, fmaf(wA11[ds], tc1, sc1));
                sc0 = n0; sc1 = n1;
            }
        }
        const int b = sw & 1;
        if (lane == 63) { totc[b][wave][0] = sc0; totc[b][wave][1] = sc1; }
        __syncthreads();   // single barrier/sweep: double-buffered totc, WAR
                           // protected by the NEXT sweep's barrier
        float sp = 100.0f, sv = 0.0f;
        for (int j = 0; j < wave; ++j) {
            const float np = fmaf(totA[j][0], sp, fmaf(totA[j][1], sv, totc[b][j][0]));
            const float nv = fmaf(totA[j][2], sp, fmaf(totA[j][3], sv, totc[b][j][1]));
            sp = np; sv = nv;
        }
        pn = fmaf(F00, sp, fmaf(F01, sv, sc0));
        const float vn = fmaf(F10, sp, fmaf(F11, sv, sc1));
        o = vn * fast_rcp(pn);
        const float rr = __shfl_up(o, 1, 64);
        r = (lane == 0) ? sv * fast_rcp(sp) : rr;
    }

    // ---- stop detection on final-sweep trajectory ----
    // first OOB pn is finite (prior state in-range); later NaNs can't mask it
    const bool hit = real && ((pn < LO_F) || (pn > HI_F));
    const unsigned long long m = __ballot(hit);
    if (lane == 0) wm[wave] = m;
    __syncthreads();

    int kstop = N_STEPS - 1;                      // covers no-hit & hit-at-last
    bool found = false;
    for (int j = 0; j < NWAVES; ++j) {
        const unsigned long long mj = wm[j];
        if (!found && mj) { kstop = j * 64 + (__ffsll(mj) - 1); found = true; }
    }

    if (real) out[k] = (k <= kstop) ? o : 0.0f;   // out emitted on hit step too
    if (tid == N_STEPS) out[N_STEPS] = (float)kstop;
}

extern "C" void kernel_launch(void* const* d_in, const int* in_sizes, int n_in,
                              void* d_out, int out_size, void* d_ws, size_t ws_size,
                              hipStream_t stream) {
    const float* inputs = (const float*)d_in[0];
    const float* fc1_w  = (const float*)d_in[1];
    const void*  tfm    = d_in[2];
    (void)in_sizes; (void)n_in; (void)out_size; (void)d_ws; (void)ws_size;

    sim_scan_kernel<<<dim3(1), dim3(NTHREADS), 0, stream>>>(
        inputs, fc1_w, tfm, (float*)d_out);
}

// Round 12
// 13.250 us; speedup vs baseline: 3.6843x; 1.2509x over previous
//
#include <hip/hip_runtime.h>

// 1001-step closed-loop sim as a PARALLEL fixed-point affine scan.
// R12: 2 steps/thread (512 threads, 8 waves). Each thread composes its two
// step-maps into a pair map; 64-lane Hillis-Steele scan over pair maps
// (sweep 0 full 6-float, saving per-round A-windows; sweeps 1+ c-only:
// 2 shuffles + 4 fma/round). Per-step outputs recovered by applying the two
// step maps from the EXCLUSIVE prefix state. One barrier/sweep via
// double-buffered c-totals (R11-proven). Lane-0 cross-wave r from own carry
// fold. Stop detection: two interleaved ballot masks, first-hit fold.

#define N_STEPS 1001
#define DT_F 0.05f
#define LO_F 0.05f
#define HI_F 1000.0f
#define NSWEEPS 5
#define NTHREADS 512
#define NWAVES 8

__device__ __forceinline__ float fast_rcp(float x) {
    return __builtin_amdgcn_rcpf(x);
}

__global__ __launch_bounds__(NTHREADS) void sim_scan_kernel(
    const float* __restrict__ inputs,
    const float* __restrict__ fc1_w,
    const void* __restrict__ tf_mask,
    float* __restrict__ out)
{
    __shared__ float totA[NWAVES][4];       // per-wave pair-A products (sweep-invariant)
    __shared__ float totc[2][NWAVES][2];    // per-wave c-totals (double-buffered)
    __shared__ int   wk[NWAVES];            // per-wave first-hit step (local idx, >=128 none)

    const int tid  = threadIdx.x;
    const int lane = tid & 63;
    const int wave = tid >> 6;
    const int k0 = 2 * tid, k1 = k0 + 1;
    const bool real0 = (k0 < N_STEPS);
    const bool real1 = (k1 < N_STEPS);

    // --- tf_mask element-width detection (per wave, same answer) ---
    // int32 0/1: bytes at i%4!=0 all zero; int64 adds i%8==4 zero; 1-byte
    // bool: ~300 random 0/1 bytes in 1..399 -> nonzero w.p. 1-2^-300.
    const unsigned char* mb = (const unsigned char*)tf_mask;
    bool nm4 = false, m84 = false;
    for (int i = 1 + lane; i < 400; i += 64) {
        unsigned char b = mb[i];
        if (b) { if ((i & 3) != 0) nm4 = true; else if ((i & 7) == 4) m84 = true; }
    }
    const int width = __any(nm4) ? 1 : (__any(m84) ? 4 : 8);

    auto ldtf = [&](int k) -> bool {
        if (width == 1) return mb[k] != 0;
        if (width == 4) return ((const int*)tf_mask)[k] != 0;
        return ((const long long*)tf_mask)[k] != 0;
    };

    // --- per-pair inputs ---
    float u0 = 0.0f, u1 = 0.0f; bool tf0 = false, tf1 = false;
    if (real1) {
        const float2 uu = *(const float2*)(inputs + k0);
        u0 = uu.x; u1 = uu.y;
        tf0 = ldtf(k0); tf1 = ldtf(k1);
    } else if (real0) {                     // thread 500: k1=1001 is pad
        u0 = inputs[k0]; tf0 = ldtf(k0);
    }

    const float w   = fc1_w[0];
    const float c1w = (DT_F * DT_F * 0.5f) * w;   // 0.00125*w
    const float dw  = DT_F * w;                    // 0.05*w

    // --- seeds: r = o_{k-1}; exact where step k-1 is teacher-forced ---
    const float al0 = fmaf(DT_F, u0, 1.0f);
    const float al1 = fmaf(DT_F, u1, 1.0f);
    float r0 = 0.0f;                               // t=0: true r = v0/p0 = 0
    if (tid > 0 && real0) {
        const float up = inputs[k0 - 1];
        if (ldtf(k0 - 1)) r0 = up * fast_rcp(fmaf(DT_F, up, 1.0f));
    }
    float r1 = tf0 ? (u0 * fast_rcp(al0)) : 0.0f;  // o_{k0} guess

    // --- sweep-invariant step A's (pads: non-tf identity-shear) ---
    const float a000 = tf0 ? al0  : 1.0f,  a001 = tf0 ? 0.0f : DT_F;
    const float a010 = tf0 ? u0   : 0.0f,  a011 = tf0 ? 0.0f : 1.0f;
    const float a100 = tf1 ? al1  : 1.0f,  a101 = tf1 ? 0.0f : DT_F;
    const float a110 = tf1 ? u1   : 0.0f,  a111 = tf1 ? 0.0f : 1.0f;
    const bool live0 = real0 && !tf0;              // select (not mul): blocks NaN leak
    const bool live1 = real1 && !tf1;

    // pair A = A1*A0 (sweep-invariant)
    const float ap00 = fmaf(a100, a000, a101 * a010);
    const float ap01 = fmaf(a100, a001, a101 * a011);
    const float ap10 = fmaf(a110, a000, a111 * a010);
    const float ap11 = fmaf(a110, a001, a111 * a011);

    float wA00[6], wA01[6], wA10[6], wA11[6];      // per-round window A products
    float E00, E01, E10, E11;                      // exclusive-prefix A (invariant)
    float o0 = 0.0f, o1 = 0.0f, pm = 100.0f, pa = 100.0f;

    // ---- sweep 0: full 6-float affine scan; save windows/totals ----
    {
        const float dd0 = u0 - r0, dd1 = u1 - r1;
        const float c00 = live0 ? c1w * dd0 : 0.0f;
        const float c01 = live0 ? dw  * dd0 : 0.0f;
        const float c10 = live1 ? c1w * dd1 : 0.0f;
        const float c11v= live1 ? dw  * dd1 : 0.0f;
        float sc0 = fmaf(a100, c00, fmaf(a101, c01, c10));  // pair c = A1*c0+c1
        float sc1 = fmaf(a110, c00, fmaf(a111, c01, c11v));
        float s00 = ap00, s01 = ap01, s10 = ap10, s11 = ap11;
#pragma unroll
        for (int ds = 0; ds < 6; ++ds) {
            const int d = 1 << ds;
            wA00[ds] = s00; wA01[ds] = s01; wA10[ds] = s10; wA11[ds] = s11;
            const float t00 = __shfl_up(s00, d, 64), t01 = __shfl_up(s01, d, 64);
            const float t10 = __shfl_up(s10, d, 64), t11 = __shfl_up(s11, d, 64);
            const float tc0 = __shfl_up(sc0, d, 64), tc1 = __shfl_up(sc1, d, 64);
            if (lane >= d) {
                const float n00 = fmaf(s00, t00, s01 * t10);
                const float n01 = fmaf(s00, t01, s01 * t11);
                const float n10 = fmaf(s10, t00, s11 * t10);
                const float n11 = fmaf(s10, t01, s11 * t11);
                const float nc0 = fmaf(s00, tc0, fmaf(s01, tc1, sc0));
                const float nc1 = fmaf(s10, tc0, fmaf(s11, tc1, sc1));
                s00 = n00; s01 = n01; s10 = n10; s11 = n11;
                sc0 = nc0; sc1 = nc1;
            }
        }
        E00 = __shfl_up(s00, 1, 64); E01 = __shfl_up(s01, 1, 64);
        E10 = __shfl_up(s10, 1, 64); E11 = __shfl_up(s11, 1, 64);
        if (lane == 0) { E00 = 1.0f; E01 = 0.0f; E10 = 0.0f; E11 = 1.0f; }
        if (lane == 63) {
            totA[wave][0] = s00; totA[wave][1] = s01;
            totA[wave][2] = s10; totA[wave][3] = s11;
            totc[0][wave][0] = sc0; totc[0][wave][1] = sc1;
        }
        __syncthreads();
        float sp = 100.0f, sv = 0.0f;              // state entering this wave
        for (int j = 0; j < wave; ++j) {
            const float np = fmaf(totA[j][0], sp, fmaf(totA[j][1], sv, totc[0][j][0]));
            const float nv = fmaf(totA[j][2], sp, fmaf(totA[j][3], sv, totc[0][j][1]));
            sp = np; sv = nv;
        }
        float ce0 = __shfl_up(sc0, 1, 64), ce1 = __shfl_up(sc1, 1, 64);
        if (lane == 0) { ce0 = 0.0f; ce1 = 0.0f; }
        const float pb = fmaf(E00, sp, fmaf(E01, sv, ce0));   // state before k0
        const float vb = fmaf(E10, sp, fmaf(E11, sv, ce1));
        pm = fmaf(a000, pb, fmaf(a001, vb, c00));             // after k0
        const float vm = fmaf(a010, pb, fmaf(a011, vb, c01));
        pa = fmaf(a100, pm, fmaf(a101, vm, c10));             // after k1
        const float va = fmaf(a110, pm, fmaf(a111, vm, c11v));
        o0 = vm * fast_rcp(pm);
        o1 = va * fast_rcp(pa);
        const float rr = __shfl_up(o1, 1, 64);
        r0 = (lane == 0) ? sv * fast_rcp(sp) : rr;            // o_{k0-1}
        r1 = o0;
    }

    // ---- sweeps 1..4: c-only scans (A windows reused) ----
    for (int sw = 1; sw < NSWEEPS; ++sw) {
        const float dd0 = u0 - r0, dd1 = u1 - r1;
        const float c00 = live0 ? c1w * dd0 : 0.0f;
        const float c01 = live0 ? dw  * dd0 : 0.0f;
        const float c10 = live1 ? c1w * dd1 : 0.0f;
        const float c11v= live1 ? dw  * dd1 : 0.0f;
        float sc0 = fmaf(a100, c00, fmaf(a101, c01, c10));
        float sc1 = fmaf(a110, c00, fmaf(a111, c01, c11v));
#pragma unroll
        for (int ds = 0; ds < 6; ++ds) {
            const int d = 1 << ds;
            const float tc0 = __shfl_up(sc0, d, 64), tc1 = __shfl_up(sc1, d, 64);
            if (lane >= d) {
                const float n0 = fmaf(wA00[ds], tc0, fmaf(wA01[ds], tc1, sc0));
                const float n1 = fmaf(wA10[ds], tc0, fmaf(wA11[ds], tc1, sc1));
                sc0 = n0; sc1 = n1;
            }
        }
        const int b = sw & 1;
        if (lane == 63) { totc[b][wave][0] = sc0; totc[b][wave][1] = sc1; }
        __syncthreads();   // single barrier/sweep (double-buffered totc)
        float sp = 100.0f, sv = 0.0f;
        for (int j = 0; j < wave; ++j) {
            const float np = fmaf(totA[j][0], sp, fmaf(totA[j][1], sv, totc[b][j][0]));
            const float nv = fmaf(totA[j][2], sp, fmaf(totA[j][3], sv, totc[b][j][1]));
            sp = np; sv = nv;
        }
        float ce0 = __shfl_up(sc0, 1, 64), ce1 = __shfl_up(sc1, 1, 64);
        if (lane == 0) { ce0 = 0.0f; ce1 = 0.0f; }
        const float pb = fmaf(E00, sp, fmaf(E01, sv, ce0));
        const float vb = fmaf(E10, sp, fmaf(E11, sv, ce1));
        pm = fmaf(a000, pb, fmaf(a001, vb, c00));
        const float vm = fmaf(a010, pb, fmaf(a011, vb, c01));
        pa = fmaf(a100, pm, fmaf(a101, vm, c10));
        const float va = fmaf(a110, pm, fmaf(a111, vm, c11v));
        o0 = vm * fast_rcp(pm);
        o1 = va * fast_rcp(pa);
        const float rr = __shfl_up(o1, 1, 64);
        r0 = (lane == 0) ? sv * fast_rcp(sp) : rr;
        r1 = o0;
    }

    // ---- stop detection: interleaved masks, first hit wins ----
    // first OOB pn is finite (prior states in-range); post-hit NaNs compare
    // false and are beyond the first hit anyway.
    const bool hit0 = real0 && ((pm < LO_F) || (pm > HI_F));
    const bool hit1 = real1 && ((pa < LO_F) || (pa > HI_F));
    const unsigned long long m0 = __ballot(hit0);
    const unsigned long long m1 = __ballot(hit1);
    if (lane == 0) {
        const int j0 = m0 ? (__ffsll(m0) - 1) : 64;
        const int j1 = m1 ? (__ffsll(m1) - 1) : 64;
        wk[wave] = (2 * j0 <= 2 * j1 + 1) ? 2 * j0 : 2 * j1 + 1;  // >=128 none
    }
    __syncthreads();

    int kstop = N_STEPS - 1;                       // covers no-hit & hit-at-last
    bool found = false;
    for (int j = 0; j < NWAVES; ++j) {
        const int c = wk[j];
        if (!found && c < 128) { kstop = j * 128 + c; found = true; }
    }

    // ---- stores (out emitted on the hit step itself; zeros after) ----
    if (real1) {
        float2 val;
        val.x = (k0 <= kstop) ? o0 : 0.0f;
        val.y = (k1 <= kstop) ? o1 : 0.0f;
        *(float2*)(out + k0) = val;
    } else if (real0) {
        out[k0] = (k0 <= kstop) ? o0 : 0.0f;       // thread 500: out[1000]
    }
    if (tid == NTHREADS - 1) out[N_STEPS] = (float)kstop;
}

extern "C" void kernel_launch(void* const* d_in, const int* in_sizes, int n_in,
                              void* d_out, int out_size, void* d_ws, size_t ws_size,
                              hipStream_t stream) {
    const float* inputs = (const float*)d_in[0];
    const float* fc1_w  = (const float*)d_in[1];
    const void*  tfm    = d_in[2];
    (void)in_sizes; (void)n_in; (void)out_size; (void)d_ws; (void)ws_size;

    sim_scan_kernel<<<dim3(1), dim3(NTHREADS), 0, stream>>>(
        inputs, fc1_w, tfm, (float*)d_out);
}

// Round 13
// 11.728 us; speedup vs baseline: 4.1626x; 1.1298x over previous
//
#include <hip/hip_runtime.h>

// 1001-step closed-loop sim as a PARALLEL fixed-point affine scan.
// R13 = R12 (2 steps/thread, 512 threads, 8 waves; sweep-invariant A-windows;
// c-only resweeps; one barrier/sweep) plus:
//   - speculative byte-view preamble: all tf loads (k0,k1,k0-1), u-pair,
//     u_prev, fc1_w issued at function top in parallel with a shortened
//     width-detection pass (byte view is in-bounds for any width at k<=1000;
//     wide widths fall back to a second load round — unlikely path)
//   - NSWEEPS 5 -> 4 (5 was bitwise-converged => contraction <~0.04/sweep;
//     4 leaves <~1e-5 error vs threshold 16.96)

#define N_STEPS 1001
#define DT_F 0.05f
#define LO_F 0.05f
#define HI_F 1000.0f
#define NSWEEPS 4
#define NTHREADS 512
#define NWAVES 8

__device__ __forceinline__ float fast_rcp(float x) {
    return __builtin_amdgcn_rcpf(x);
}

__global__ __launch_bounds__(NTHREADS) void sim_scan_kernel(
    const float* __restrict__ inputs,
    const float* __restrict__ fc1_w,
    const void* __restrict__ tf_mask,
    float* __restrict__ out)
{
    __shared__ float totA[NWAVES][4];       // per-wave pair-A products (sweep-invariant)
    __shared__ float totc[2][NWAVES][2];    // per-wave c-totals (double-buffered)
    __shared__ int   wk[NWAVES];            // per-wave first-hit step (local idx, >=128 none)

    const int tid  = threadIdx.x;
    const int lane = tid & 63;
    const int wave = tid >> 6;
    const int k0 = 2 * tid, k1 = k0 + 1;
    const bool real0 = (k0 < N_STEPS);
    const bool real1 = (k1 < N_STEPS);

    // ---- issue ALL likely-path global loads up front (parallel misses) ----
    const unsigned char* mb = (const unsigned char*)tf_mask;
    const float wHot = fc1_w[0];
    float u0 = 0.0f, u1 = 0.0f, up = 0.0f;
    if (real1) { const float2 uu = *(const float2*)(inputs + k0); u0 = uu.x; u1 = uu.y; }
    else if (real0) u0 = inputs[k0];
    if (tid > 0 && real0) up = inputs[k0 - 1];
    // byte-view tf loads: in-bounds for ANY element width (k <= 1000)
    unsigned char tb0 = real0 ? mb[k0] : 0;
    unsigned char tb1 = real1 ? mb[k1] : 0;
    unsigned char tbp = (tid > 0 && real0) ? mb[k0 - 1] : 0;

    // ---- width detection, overlapped with the loads above ----
    // sample 256 bytes: 1-byte bool has ~192 random 0/1 bytes at off%4!=0 ->
    // miss prob ~2^-192; int32 0/1 has those bytes all zero; int64 adds
    // off%8==4 zero.
    bool nm4 = false, m84 = false;
    {
        const int i0 = 1 + lane, i1 = i0 + 64, i2 = i0 + 128, i3 = i0 + 192;
        const unsigned char b0 = mb[i0], b1 = mb[i1], b2 = mb[i2], b3 = mb[i3];
        if (b0) { if ((i0 & 3) != 0) nm4 = true; else if ((i0 & 7) == 4) m84 = true; }
        if (b1) { if ((i1 & 3) != 0) nm4 = true; else if ((i1 & 7) == 4) m84 = true; }
        if (b2) { if ((i2 & 3) != 0) nm4 = true; else if ((i2 & 7) == 4) m84 = true; }
        if (b3) { if ((i3 & 3) != 0) nm4 = true; else if ((i3 & 7) == 4) m84 = true; }
    }
    const int width = __any(nm4) ? 1 : (__any(m84) ? 4 : 8);

    bool tf0, tf1, tfp;
    if (width == 1) {            // expected path: speculative loads are correct
        tf0 = tb0 != 0; tf1 = tb1 != 0; tfp = tbp != 0;
    } else if (width == 4) {     // fallback: one extra load round
        const int* ti = (const int*)tf_mask;
        tf0 = real0 && ti[k0] != 0;
        tf1 = real1 && ti[k1] != 0;
        tfp = (tid > 0 && real0) && ti[k0 - 1] != 0;
    } else {
        const long long* tl = (const long long*)tf_mask;
        tf0 = real0 && tl[k0] != 0;
        tf1 = real1 && tl[k1] != 0;
        tfp = (tid > 0 && real0) && tl[k0 - 1] != 0;
    }

    const float w   = wHot;
    const float c1w = (DT_F * DT_F * 0.5f) * w;   // 0.00125*w
    const float dw  = DT_F * w;                    // 0.05*w

    // --- seeds: r = o_{k-1}; exact where step k-1 is teacher-forced ---
    const float al0 = fmaf(DT_F, u0, 1.0f);
    const float al1 = fmaf(DT_F, u1, 1.0f);
    float r0 = (tfp) ? up * fast_rcp(fmaf(DT_F, up, 1.0f)) : 0.0f;  // t=0 lane: 0
    float r1 = tf0 ? (u0 * fast_rcp(al0)) : 0.0f;  // o_{k0} guess

    // --- sweep-invariant step A's (pads: non-tf identity-shear) ---
    const float a000 = tf0 ? al0  : 1.0f,  a001 = tf0 ? 0.0f : DT_F;
    const float a010 = tf0 ? u0   : 0.0f,  a011 = tf0 ? 0.0f : 1.0f;
    const float a100 = tf1 ? al1  : 1.0f,  a101 = tf1 ? 0.0f : DT_F;
    const float a110 = tf1 ? u1   : 0.0f,  a111 = tf1 ? 0.0f : 1.0f;
    const bool live0 = real0 && !tf0;              // select (not mul): blocks NaN leak
    const bool live1 = real1 && !tf1;

    // pair A = A1*A0 (sweep-invariant)
    const float ap00 = fmaf(a100, a000, a101 * a010);
    const float ap01 = fmaf(a100, a001, a101 * a011);
    const float ap10 = fmaf(a110, a000, a111 * a010);
    const float ap11 = fmaf(a110, a001, a111 * a011);

    float wA00[6], wA01[6], wA10[6], wA11[6];      // per-round window A products
    float E00, E01, E10, E11;                      // exclusive-prefix A (invariant)
    float o0 = 0.0f, o1 = 0.0f, pm = 100.0f, pa = 100.0f;

    // ---- sweep 0: full 6-float affine scan; save windows/totals ----
    {
        const float dd0 = u0 - r0, dd1 = u1 - r1;
        const float c00 = live0 ? c1w * dd0 : 0.0f;
        const float c01 = live0 ? dw  * dd0 : 0.0f;
        const float c10 = live1 ? c1w * dd1 : 0.0f;
        const float c11v= live1 ? dw  * dd1 : 0.0f;
        float sc0 = fmaf(a100, c00, fmaf(a101, c01, c10));  // pair c = A1*c0+c1
        float sc1 = fmaf(a110, c00, fmaf(a111, c01, c11v));
        float s00 = ap00, s01 = ap01, s10 = ap10, s11 = ap11;
#pragma unroll
        for (int ds = 0; ds < 6; ++ds) {
            const int d = 1 << ds;
            wA00[ds] = s00; wA01[ds] = s01; wA10[ds] = s10; wA11[ds] = s11;
            const float t00 = __shfl_up(s00, d, 64), t01 = __shfl_up(s01, d, 64);
            const float t10 = __shfl_up(s10, d, 64), t11 = __shfl_up(s11, d, 64);
            const float tc0 = __shfl_up(sc0, d, 64), tc1 = __shfl_up(sc1, d, 64);
            if (lane >= d) {
                const float n00 = fmaf(s00, t00, s01 * t10);
                const float n01 = fmaf(s00, t01, s01 * t11);
                const float n10 = fmaf(s10, t00, s11 * t10);
                const float n11 = fmaf(s10, t01, s11 * t11);
                const float nc0 = fmaf(s00, tc0, fmaf(s01, tc1, sc0));
                const float nc1 = fmaf(s10, tc0, fmaf(s11, tc1, sc1));
                s00 = n00; s01 = n01; s10 = n10; s11 = n11;
                sc0 = nc0; sc1 = nc1;
            }
        }
        E00 = __shfl_up(s00, 1, 64); E01 = __shfl_up(s01, 1, 64);
        E10 = __shfl_up(s10, 1, 64); E11 = __shfl_up(s11, 1, 64);
        if (lane == 0) { E00 = 1.0f; E01 = 0.0f; E10 = 0.0f; E11 = 1.0f; }
        if (lane == 63) {
            totA[wave][0] = s00; totA[wave][1] = s01;
            totA[wave][2] = s10; totA[wave][3] = s11;
            totc[0][wave][0] = sc0; totc[0][wave][1] = sc1;
        }
        __syncthreads();
        float sp = 100.0f, sv = 0.0f;              // state entering this wave
        for (int j = 0; j < wave; ++j) {
            const float np = fmaf(totA[j][0], sp, fmaf(totA[j][1], sv, totc[0][j][0]));
            const float nv = fmaf(totA[j][2], sp, fmaf(totA[j][3], sv, totc[0][j][1]));
            sp = np; sv = nv;
        }
        float ce0 = __shfl_up(sc0, 1, 64), ce1 = __shfl_up(sc1, 1, 64);
        if (lane == 0) { ce0 = 0.0f; ce1 = 0.0f; }
        const float pb = fmaf(E00, sp, fmaf(E01, sv, ce0));   // state before k0
        const float vb = fmaf(E10, sp, fmaf(E11, sv, ce1));
        pm = fmaf(a000, pb, fmaf(a001, vb, c00));             // after k0
        const float vm = fmaf(a010, pb, fmaf(a011, vb, c01));
        pa = fmaf(a100, pm, fmaf(a101, vm, c10));             // after k1
        const float va = fmaf(a110, pm, fmaf(a111, vm, c11v));
        o0 = vm * fast_rcp(pm);
        o1 = va * fast_rcp(pa);
        const float rr = __shfl_up(o1, 1, 64);
        r0 = (lane == 0) ? sv * fast_rcp(sp) : rr;            // o_{k0-1}
        r1 = o0;
    }

    // ---- sweeps 1..NSWEEPS-1: c-only scans (A windows reused) ----
    for (int sw = 1; sw < NSWEEPS; ++sw) {
        const float dd0 = u0 - r0, dd1 = u1 - r1;
        const float c00 = live0 ? c1w * dd0 : 0.0f;
        const float c01 = live0 ? dw  * dd0 : 0.0f;
        const float c10 = live1 ? c1w * dd1 : 0.0f;
        const float c11v= live1 ? dw  * dd1 : 0.0f;
        float sc0 = fmaf(a100, c00, fmaf(a101, c01, c10));
        float sc1 = fmaf(a110, c00, fmaf(a111, c01, c11v));
#pragma unroll
        for (int ds = 0; ds < 6; ++ds) {
            const int d = 1 << ds;
            const float tc0 = __shfl_up(sc0, d, 64), tc1 = __shfl_up(sc1, d, 64);
            if (lane >= d) {
                const float n0 = fmaf(wA00[ds], tc0, fmaf(wA01[ds], tc1, sc0));
                const float n1 = fmaf(wA10[ds], tc0, fmaf(wA11[ds], tc1, sc1));
                sc0 = n0; sc1 = n1;
            }
        }
        const int b = sw & 1;
        if (lane == 63) { totc[b][wave][0] = sc0; totc[b][wave][1] = sc1; }
        __syncthreads();   // single barrier/sweep (double-buffered totc)
        float sp = 100.0f, sv = 0.0f;
        for (int j = 0; j < wave; ++j) {
            const float np = fmaf(totA[j][0], sp, fmaf(totA[j][1], sv, totc[b][j][0]));
            const float nv = fmaf(totA[j][2], sp, fmaf(totA[j][3], sv, totc[b][j][1]));
            sp = np; sv = nv;
        }
        float ce0 = __shfl_up(sc0, 1, 64), ce1 = __shfl_up(sc1, 1, 64);
        if (lane == 0) { ce0 = 0.0f; ce1 = 0.0f; }
        const float pb = fmaf(E00, sp, fmaf(E01, sv, ce0));
        const float vb = fmaf(E10, sp, fmaf(E11, sv, ce1));
        pm = fmaf(a000, pb, fmaf(a001, vb, c00));
        const float vm = fmaf(a010, pb, fmaf(a011, vb, c01));
        pa = fmaf(a100, pm, fmaf(a101, vm, c10));
        const float va = fmaf(a110, pm, fmaf(a111, vm, c11v));
        o0 = vm * fast_rcp(pm);
        o1 = va * fast_rcp(pa);
        const float rr = __shfl_up(o1, 1, 64);
        r0 = (lane == 0) ? sv * fast_rcp(sp) : rr;
        r1 = o0;
    }

    // ---- stop detection: interleaved masks, first hit wins ----
    // first OOB pn is finite (prior states in-range); post-hit NaNs compare
    // false and are beyond the first hit anyway.
    const bool hit0 = real0 && ((pm < LO_F) || (pm > HI_F));
    const bool hit1 = real1 && ((pa < LO_F) || (pa > HI_F));
    const unsigned long long m0 = __ballot(hit0);
    const unsigned long long m1 = __ballot(hit1);
    if (lane == 0) {
        const int j0 = m0 ? (__ffsll(m0) - 1) : 64;
        const int j1 = m1 ? (__ffsll(m1) - 1) : 64;
        wk[wave] = (2 * j0 <= 2 * j1 + 1) ? 2 * j0 : 2 * j1 + 1;  // >=128 none
    }
    __syncthreads();

    int kstop = N_STEPS - 1;                       // covers no-hit & hit-at-last
    bool found = false;
    for (int j = 0; j < NWAVES; ++j) {
        const int c = wk[j];
        if (!found && c < 128) { kstop = j * 128 + c; found = true; }
    }

    // ---- stores (out emitted on the hit step itself; zeros after) ----
    if (real1) {
        float2 val;
        val.x = (k0 <= kstop) ? o0 : 0.0f;
        val.y = (k1 <= kstop) ? o1 : 0.0f;
        *(float2*)(out + k0) = val;
    } else if (real0) {
        out[k0] = (k0 <= kstop) ? o0 : 0.0f;       // thread 500: out[1000]
    }
    if (tid == NTHREADS - 1) out[N_STEPS] = (float)kstop;
}

extern "C" void kernel_launch(void* const* d_in, const int* in_sizes, int n_in,
                              void* d_out, int out_size, void* d_ws, size_t ws_size,
                              hipStream_t stream) {
    const float* inputs = (const float*)d_in[0];
    const float* fc1_w  = (const float*)d_in[1];
    const void*  tfm    = d_in[2];
    (void)in_sizes; (void)n_in; (void)out_size; (void)d_ws; (void)ws_size;

    sim_scan_kernel<<<dim3(1), dim3(NTHREADS), 0, stream>>>(
        inputs, fc1_w, tfm, (float*)d_out);
}